// Round 3
// baseline (270.235 us; speedup 1.0000x reference)
//
#include <hip/hip_runtime.h>
#include <hip/hip_bf16.h>
#include <type_traits>

// Dims: B=8, L=2048, T=1024, Dh=1024, Dg=768, Dp=256
// Pipeline: casts; [HT,Hbf]=transpose(H); Q=Gbf@Wqbf^T (pre proj); K=Hbf@Wkbf^T;
//           Z = flash_attn(Q,K,HT)  -- fused S/softmax/PV, no S materialization.
// Workspace (u16): Qbf 2M | Kbf 4M | HT 16M | Hbf 16M | Gbf 6M | Wqbf | Wkbf

typedef float    f32x4  __attribute__((ext_vector_type(4)));
typedef __bf16   bf16x8 __attribute__((ext_vector_type(8)));
typedef unsigned short u16x8 __attribute__((ext_vector_type(8)));

__device__ __forceinline__ unsigned short f2bf(float f) {
    union { float f; unsigned u; } x; x.f = f;
    return (unsigned short)((x.u + 0x7fffu + ((x.u >> 16) & 1u)) >> 16);
}
__device__ __forceinline__ float bf2f(unsigned short u) {
    union { unsigned u; float f; } x; x.u = ((unsigned)u) << 16;
    return x.f;
}

__device__ __forceinline__ void gload_lds16(const unsigned short* g, unsigned short* l) {
    __builtin_amdgcn_global_load_lds(
        (const __attribute__((address_space(1))) void*)g,
        (__attribute__((address_space(3))) void*)l, 16, 0, 0);
}

// ---------------- f32 -> bf16 cast ----------------
__global__ __launch_bounds__(256) void cast_bf16(const float* __restrict__ in,
                                                 unsigned short* __restrict__ out, int n8) {
    int i = blockIdx.x * 256 + threadIdx.x;
    if (i >= n8) return;
    const f32x4* p = (const f32x4*)(in + (size_t)i * 8);
    f32x4 a = p[0], b = p[1];
    u16x8 o;
#pragma unroll
    for (int j = 0; j < 4; ++j) { o[j] = f2bf(a[j]); o[4 + j] = f2bf(b[j]); }
    *(u16x8*)(out + (size_t)i * 8) = o;
}

// ------- transpose + dual cast: H [L,Dh] f32 -> HT [Dh,L] bf16 AND Hbf [L,Dh] bf16 -------
__global__ __launch_bounds__(256) void transpose_cast(const float* __restrict__ H,
                                                      unsigned short* __restrict__ HT,
                                                      unsigned short* __restrict__ Hbf,
                                                      int L, int D) {
    __shared__ float tile[32][33];
    int b = blockIdx.z;
    const float* src = H + (size_t)b * L * D;
    unsigned short* dstT = HT + (size_t)b * L * D;
    unsigned short* dstN = Hbf + (size_t)b * L * D;
    int l0 = blockIdx.y * 32, d0 = blockIdx.x * 32;
    int tx = threadIdx.x, ty = threadIdx.y;
#pragma unroll
    for (int i = ty; i < 32; i += 8) {
        float v = src[(size_t)(l0 + i) * D + d0 + tx];
        tile[i][tx] = v;
        dstN[(size_t)(l0 + i) * D + d0 + tx] = f2bf(v);
    }
    __syncthreads();
#pragma unroll
    for (int i = ty; i < 32; i += 8)
        dstT[(size_t)(d0 + i) * L + l0 + tx] = f2bf(tile[tx][i]);
}

// ---------------- m97-structure GEMM (projections): C = A @ B^T ----------------
template<typename TC, bool BATCH8>
__global__ __launch_bounds__(256) void gemm_lds(const unsigned short* __restrict__ A,
                                                const unsigned short* __restrict__ B,
                                                TC* __restrict__ C,
                                                int N, int K,
                                                long batchA, long batchB, long batchC,
                                                float scale, int gxs) {
    __shared__ unsigned short sA[128 * 32];
    __shared__ unsigned short sB[128 * 32];
    int tid = threadIdx.x;
    int wg = blockIdx.x;
    int bz, t;
    if constexpr (BATCH8) { bz = wg & 7; t = wg >> 3; }
    else                  { bz = 0;      t = wg;      }
    int by = t >> gxs;
    int bx = t & ((1 << gxs) - 1);

    const unsigned short* Ab = A + (size_t)bz * batchA + (size_t)by * 128 * K;
    const unsigned short* Bb = B + (size_t)bz * batchB + (size_t)bx * 128 * K;
    TC* Cb = C + (size_t)bz * batchC;

    int lane = tid & 63;
    int wid = tid >> 6;
    int wr = wid >> 1, wc = wid & 1;
    int lr = lane & 15;
    int lk = (lane >> 4) * 8;

    f32x4 acc[4][4] = {};

    for (int k0 = 0; k0 < K; k0 += 32) {
#pragma unroll
        for (int c = 0; c < 2; ++c) {
            int t16 = c * 256 + tid;
            int row = t16 >> 2;
            int col = (t16 & 3) * 8;
            gload_lds16(Ab + (size_t)row * K + k0 + col, &sA[t16 * 8]);
            gload_lds16(Bb + (size_t)row * K + k0 + col, &sB[t16 * 8]);
        }
        __syncthreads();
        bf16x8 af[4], bfr[4];
#pragma unroll
        for (int m = 0; m < 4; ++m)
            af[m] = *reinterpret_cast<const bf16x8*>(&sA[(wr * 64 + m * 16 + lr) * 32 + lk]);
#pragma unroll
        for (int n = 0; n < 4; ++n)
            bfr[n] = *reinterpret_cast<const bf16x8*>(&sB[(wc * 64 + n * 16 + lr) * 32 + lk]);
#pragma unroll
        for (int m = 0; m < 4; ++m)
#pragma unroll
            for (int n = 0; n < 4; ++n)
                acc[m][n] = __builtin_amdgcn_mfma_f32_16x16x32_bf16(af[m], bfr[n], acc[m][n], 0, 0, 0);
        __syncthreads();
    }

#pragma unroll
    for (int m = 0; m < 4; ++m) {
        int r0 = by * 128 + wr * 64 + m * 16 + (lane >> 4) * 4;
#pragma unroll
        for (int n = 0; n < 4; ++n) {
            int c0 = bx * 128 + wc * 64 + n * 16 + (lane & 15);
#pragma unroll
            for (int j = 0; j < 4; ++j) {
                float v = acc[m][n][j] * scale;
                if constexpr (std::is_same_v<TC, float>)
                    Cb[(size_t)(r0 + j) * N + c0] = v;
                else
                    Cb[(size_t)(r0 + j) * N + c0] = f2bf(v);
            }
        }
    }
}

// ---------------- fused flash attention ----------------
// Grid: (T/32)*B blocks, b = wg&7 (XCD-clustered). Block: 512 thr = 8 waves.
// Wave w owns Dh-slice [w*128, (w+1)*128). Q-tile 32 rows (pre-scaled 1/16) in LDS.
// Per KV-tile (128): wave w computes S cols [16w,16w+16) -> S_lds (f32);
// cross-wave online softmax via LDS stats; P (bf16) in LDS; PV with B-frags from HT.
__global__ __launch_bounds__(512) void flash_attn(const unsigned short* __restrict__ Qb,
                                                  const unsigned short* __restrict__ Kb,
                                                  const unsigned short* __restrict__ HTb,
                                                  float* __restrict__ Zb) {
    constexpr int L = 2048, T = 1024, Dh = 1024, Dp = 256;
    constexpr int QS = 264;  // Q_lds row stride (u16): 528B -> bank step 4, 2-way max
    constexpr int SS = 132;  // S_lds row stride (f32)
    constexpr int PS = 136;  // P_lds row stride (u16): 272B -> bank step 4

    __shared__ unsigned short Qs[32 * QS];
    __shared__ float          Ss[32 * SS];
    __shared__ unsigned short Ps[32 * PS];
    __shared__ float m_s[32], l_s[32], f_s[32];

    int wg = blockIdx.x;
    int b = wg & 7;
    int t0 = (wg >> 3) * 32;

    const unsigned short* Q  = Qb  + ((size_t)b * T + t0) * Dp;
    const unsigned short* K  = Kb  + (size_t)b * L * Dp;
    const unsigned short* HT = HTb + (size_t)b * Dh * L;
    float*                Z  = Zb  + ((size_t)b * T + t0) * Dh;

    int tid  = threadIdx.x;
    int lane = tid & 63;
    int w    = tid >> 6;
    int lg   = lane >> 4;      // k-group 0..3
    int lc   = lane & 15;      // row/col within frag

    // ---- load Q-tile, pre-scaled by Dp^-0.5 = 1/16 (exact pow2) ----
    for (int i = tid; i < 32 * 32; i += 512) {
        int row = i >> 5, col = (i & 31) * 8;
        u16x8 v = *(const u16x8*)(Q + (size_t)row * Dp + col);
        u16x8 o;
#pragma unroll
        for (int j = 0; j < 8; ++j) o[j] = f2bf(bf2f(v[j]) * 0.0625f);
        *(u16x8*)(&Qs[row * QS + col]) = o;
    }
    if (tid < 32) { m_s[tid] = -INFINITY; l_s[tid] = 0.f; }
    __syncthreads();

    f32x4 acc[2][8] = {};
    int srow = w * 4 + lg;         // softmax row for this thread
    int c8   = lc * 8;             // softmax col group

    for (int kt = 0; kt < 16; ++kt) {
        int kv0 = kt * 128;

        // ---- QK^T: wave w -> S cols [16w, 16w+16) ----
        f32x4 s0 = {}, s1 = {};
        const unsigned short* Kw = K + (size_t)(kv0 + w * 16 + lc) * Dp + lg * 8;
#pragma unroll
        for (int ks = 0; ks < 8; ++ks) {
            bf16x8 bfrag = *(const bf16x8*)(Kw + ks * 32);
            bf16x8 a0 = *(const bf16x8*)(&Qs[lc * QS + ks * 32 + lg * 8]);
            bf16x8 a1 = *(const bf16x8*)(&Qs[(16 + lc) * QS + ks * 32 + lg * 8]);
            s0 = __builtin_amdgcn_mfma_f32_16x16x32_bf16(a0, bfrag, s0, 0, 0, 0);
            s1 = __builtin_amdgcn_mfma_f32_16x16x32_bf16(a1, bfrag, s1, 0, 0, 0);
        }
#pragma unroll
        for (int j = 0; j < 4; ++j) {
            Ss[(lg * 4 + j) * SS + w * 16 + lc]        = s0[j];
            Ss[(16 + lg * 4 + j) * SS + w * 16 + lc]   = s1[j];
        }
        __syncthreads();

        // ---- online softmax: 16 threads per row ----
        f32x4 va = *(const f32x4*)(&Ss[srow * SS + c8]);
        f32x4 vb = *(const f32x4*)(&Ss[srow * SS + c8 + 4]);
        float mt = fmaxf(fmaxf(fmaxf(va[0], va[1]), fmaxf(va[2], va[3])),
                         fmaxf(fmaxf(vb[0], vb[1]), fmaxf(vb[2], vb[3])));
#pragma unroll
        for (int off = 1; off < 16; off <<= 1) mt = fmaxf(mt, __shfl_xor(mt, off));
        float mo = m_s[srow];
        float mn = fmaxf(mo, mt);
        float p[8], sum = 0.f;
#pragma unroll
        for (int j = 0; j < 4; ++j) { p[j] = __expf(va[j] - mn); sum += p[j]; }
#pragma unroll
        for (int j = 0; j < 4; ++j) { p[4 + j] = __expf(vb[j] - mn); sum += p[4 + j]; }
#pragma unroll
        for (int off = 1; off < 16; off <<= 1) sum += __shfl_xor(sum, off);
        u16x8 po;
#pragma unroll
        for (int j = 0; j < 8; ++j) po[j] = f2bf(p[j]);
        *(u16x8*)(&Ps[srow * PS + c8]) = po;
        if (lc == 0) {
            float f = __expf(mo - mn);   // 1.0 if max unchanged; 0.0 on first tile
            f_s[srow] = f;
            m_s[srow] = mn;
            l_s[srow] = l_s[srow] * f + sum;
        }
        __syncthreads();

        // ---- rescale acc (skipped when no row max grew) ----
        float fr[2][4];
#pragma unroll
        for (int m = 0; m < 2; ++m)
#pragma unroll
            for (int j = 0; j < 4; ++j)
                fr[m][j] = f_s[m * 16 + lg * 4 + j];
        bool ne = false;
#pragma unroll
        for (int m = 0; m < 2; ++m)
#pragma unroll
            for (int j = 0; j < 4; ++j) ne |= (fr[m][j] != 1.0f);
        if (__any(ne)) {
#pragma unroll
            for (int m = 0; m < 2; ++m)
#pragma unroll
                for (int n = 0; n < 8; ++n)
#pragma unroll
                    for (int j = 0; j < 4; ++j) acc[m][n][j] *= fr[m][j];
        }

        // ---- PV: wave w accumulates its Dh-slice [w*128, w*128+128) ----
        const unsigned short* HTw = HT + (size_t)(w * 128 + lc) * L + kv0 + lg * 8;
#pragma unroll
        for (int ks = 0; ks < 4; ++ks) {
            bf16x8 a0 = *(const bf16x8*)(&Ps[lc * PS + ks * 32 + lg * 8]);
            bf16x8 a1 = *(const bf16x8*)(&Ps[(16 + lc) * PS + ks * 32 + lg * 8]);
#pragma unroll
            for (int n = 0; n < 8; ++n) {
                bf16x8 bfr = *(const bf16x8*)(HTw + (size_t)n * 16 * L + ks * 32);
                acc[0][n] = __builtin_amdgcn_mfma_f32_16x16x32_bf16(a0, bfr, acc[0][n], 0, 0, 0);
                acc[1][n] = __builtin_amdgcn_mfma_f32_16x16x32_bf16(a1, bfr, acc[1][n], 0, 0, 0);
            }
        }
        // next-iter QK S-writes are fenced from this iter's softmax S-reads by the
        // post-softmax barrier; P-writes(k+1) fenced from PV P-reads(k) by post-QK barrier.
    }

    // ---- epilogue: Z = acc / l ----
    float linv[2][4];
#pragma unroll
    for (int m = 0; m < 2; ++m)
#pragma unroll
        for (int j = 0; j < 4; ++j)
            linv[m][j] = 1.0f / l_s[m * 16 + lg * 4 + j];
#pragma unroll
    for (int m = 0; m < 2; ++m) {
        int r0 = m * 16 + lg * 4;
#pragma unroll
        for (int n = 0; n < 8; ++n) {
            int c0 = w * 128 + n * 16 + lc;
#pragma unroll
            for (int j = 0; j < 4; ++j)
                Z[(size_t)(r0 + j) * Dh + c0] = acc[m][n][j] * linv[m][j];
        }
    }
}

extern "C" void kernel_launch(void* const* d_in, const int* in_sizes, int n_in,
                              void* d_out, int out_size, void* d_ws, size_t ws_size,
                              hipStream_t stream) {
    constexpr int B = 8, L = 2048, T = 1024, Dh = 1024, Dg = 768, Dp = 256;
    const float* H  = (const float*)d_in[0];
    const float* G  = (const float*)d_in[1];
    const float* Wq = (const float*)d_in[2];
    const float* Wk = (const float*)d_in[3];
    float* Z = (float*)d_out;

    unsigned short* Qbf  = (unsigned short*)d_ws;                 // B*T*Dp
    unsigned short* Kbf  = Qbf  + (size_t)B * T * Dp;             // B*L*Dp
    unsigned short* HT   = Kbf  + (size_t)B * L * Dp;             // B*Dh*L
    unsigned short* Hbf  = HT   + (size_t)B * Dh * L;             // B*L*Dh
    unsigned short* Gbf  = Hbf  + (size_t)B * (size_t)L * Dh;     // B*T*Dg
    unsigned short* Wqbf = Gbf  + (size_t)B * T * Dg;             // Dp*Dg
    unsigned short* Wkbf = Wqbf + (size_t)Dp * Dg;                // Dp*Dh

    cast_bf16<<<(B * T * Dg / 8 + 255) / 256, 256, 0, stream>>>(G, Gbf, B * T * Dg / 8);
    cast_bf16<<<(Dp * Dg / 8 + 255) / 256, 256, 0, stream>>>(Wq, Wqbf, Dp * Dg / 8);
    cast_bf16<<<(Dp * Dh / 8 + 255) / 256, 256, 0, stream>>>(Wk, Wkbf, Dp * Dh / 8);

    transpose_cast<<<dim3(Dh / 32, L / 32, B), dim3(32, 8), 0, stream>>>(H, HT, Hbf, L, Dh);

    // Q = Gbf @ Wqbf^T  [B*T, Dp]
    gemm_lds<unsigned short, false><<<(Dp / 128) * (B * T / 128), 256, 0, stream>>>
        (Gbf, Wqbf, Qbf, Dp, Dg, 0, 0, 0, 1.0f, 1);

    // K = Hbf @ Wkbf^T  [B*L, Dp]
    gemm_lds<unsigned short, false><<<(Dp / 128) * (B * L / 128), 256, 0, stream>>>
        (Hbf, Wkbf, Kbf, Dp, Dh, 0, 0, 0, 1.0f, 1);

    // Z = flash(Q, K, HT)
    flash_attn<<<(T / 32) * B, 512, 0, stream>>>(Qbf, Kbf, HT, Z);
}

// Round 4
// 224.085 us; speedup vs baseline: 1.2059x; 1.2059x over previous
//
#include <hip/hip_runtime.h>
#include <hip/hip_bf16.h>
#include <type_traits>

// Dims: B=8, L=2048, T=1024, Dh=1024, Dg=768, Dp=256
// Pipeline (all-bf16 MFMA GEMMs, m97 structure + BK=64 + XOR-swizzled LDS +
// LDS-routed coalesced epilogue):
//   Gbf,Wqbf,Wkbf = cast(G,Wq,Wk); [HT,Hbf] = transpose+cast(H)
//   Q = Gbf@Wqbf^T; K = Hbf@Wkbf^T; S = softmax(Q@K^T/16); Z = S@HT^T (f32 out)
// Workspace (u16): Qbf 2M | Kbf 4M | HT 16M | Hbf 16M | {S overlays Hbf}... S separate:
//   Qbf 2M | Kbf 4M | HT 16M | Hbf 16M | Gbf 6M | Wqbf | Wkbf | S 16M  ~= 125MB

typedef float    f32x4  __attribute__((ext_vector_type(4)));
typedef __bf16   bf16x8 __attribute__((ext_vector_type(8)));
typedef unsigned short u16x8 __attribute__((ext_vector_type(8)));

__device__ __forceinline__ unsigned short f2bf(float f) {
    union { float f; unsigned u; } x; x.f = f;
    return (unsigned short)((x.u + 0x7fffu + ((x.u >> 16) & 1u)) >> 16);
}
__device__ __forceinline__ float bf2f(unsigned short u) {
    union { unsigned u; float f; } x; x.u = ((unsigned)u) << 16;
    return x.f;
}

__device__ __forceinline__ void gload_lds16(const unsigned short* g, unsigned short* l) {
    __builtin_amdgcn_global_load_lds(
        (const __attribute__((address_space(1))) void*)g,
        (__attribute__((address_space(3))) void*)l, 16, 0, 0);
}

// ---------------- f32 -> bf16 cast ----------------
__global__ __launch_bounds__(256) void cast_bf16(const float* __restrict__ in,
                                                 unsigned short* __restrict__ out, int n8) {
    int i = blockIdx.x * 256 + threadIdx.x;
    if (i >= n8) return;
    const f32x4* p = (const f32x4*)(in + (size_t)i * 8);
    f32x4 a = p[0], b = p[1];
    u16x8 o;
#pragma unroll
    for (int j = 0; j < 4; ++j) { o[j] = f2bf(a[j]); o[4 + j] = f2bf(b[j]); }
    *(u16x8*)(out + (size_t)i * 8) = o;
}

// ------- transpose + dual cast: H [L,Dh] f32 -> HT [Dh,L] bf16 AND Hbf [L,Dh] bf16 -------
__global__ __launch_bounds__(256) void transpose_cast(const float* __restrict__ H,
                                                      unsigned short* __restrict__ HT,
                                                      unsigned short* __restrict__ Hbf,
                                                      int L, int D) {
    __shared__ float tile[32][33];
    int b = blockIdx.z;
    const float* src = H + (size_t)b * L * D;
    unsigned short* dstT = HT + (size_t)b * L * D;
    unsigned short* dstN = Hbf + (size_t)b * L * D;
    int l0 = blockIdx.y * 32, d0 = blockIdx.x * 32;
    int tx = threadIdx.x, ty = threadIdx.y;
#pragma unroll
    for (int i = ty; i < 32; i += 8) {
        float v = src[(size_t)(l0 + i) * D + d0 + tx];
        tile[i][tx] = v;
        dstN[(size_t)(l0 + i) * D + d0 + tx] = f2bf(v);
    }
    __syncthreads();
#pragma unroll
    for (int i = ty; i < 32; i += 8)
        dstT[(size_t)(d0 + i) * L + l0 + tx] = f2bf(tile[tx][i]);
}

// ---------------- GEMM: C[M,N] = scale * A[M,K] @ B^T[N,K], bf16 in ----------------
// 128x128 tile, BK=64, 4 waves. global_load_lds w16 with pre-swizzled source
// (chunk c8 ^= row&7 within each 128B row), frag reads XOR the same involution
// -> 2-way banks (free). LDS-routed epilogue: acc -> f32 LDS (stride 132) in two
// wr-phases, read back row-major, coalesced vector stores (nt for f32/Z).
template<typename TC, bool BATCH8>
__global__ __launch_bounds__(256) void gemm_lds(const unsigned short* __restrict__ A,
                                                const unsigned short* __restrict__ B,
                                                TC* __restrict__ C,
                                                int N, int K,
                                                long batchA, long batchB, long batchC,
                                                float scale, int gxs) {
    __shared__ __align__(16) char smem_raw[64 * 132 * 4];   // 33792B >= 2*8KB K-tiles
    unsigned short* sA = (unsigned short*)smem_raw;          // 128x64 u16 = 16KB
    unsigned short* sB = sA + 128 * 64;                      // 16KB
    float* st = (float*)smem_raw;                            // epilogue staging 64x132 f32

    int tid = threadIdx.x;
    int wg = blockIdx.x;
    int bz, t;
    if constexpr (BATCH8) { bz = wg & 7; t = wg >> 3; }
    else                  { bz = 0;      t = wg;      }
    int by = t >> gxs;
    int bx = t & ((1 << gxs) - 1);

    const unsigned short* Ab = A + (size_t)bz * batchA + (size_t)by * 128 * K;
    const unsigned short* Bb = B + (size_t)bz * batchB + (size_t)bx * 128 * K;
    TC* Cb = C + (size_t)bz * batchC;

    int lane = tid & 63;
    int wid = tid >> 6;
    int wr = wid >> 1, wc = wid & 1;
    int lr = lane & 15;
    int lg = lane >> 4;          // 0..3
    int xoff = (lane & 7) << 3;  // swizzle XOR for frag reads (u16 units)

    f32x4 acc[4][4] = {};

    for (int k0 = 0; k0 < K; k0 += 64) {
#pragma unroll
        for (int c = 0; c < 4; ++c) {
            int t16 = c * 256 + tid;                 // 16B chunk id in 16KB tile
            int row = t16 >> 3;
            int g8  = (t16 & 7) ^ (row & 7);         // pre-swizzled source chunk
            gload_lds16(Ab + (size_t)row * K + k0 + g8 * 8, sA + t16 * 8);
            gload_lds16(Bb + (size_t)row * K + k0 + g8 * 8, sB + t16 * 8);
        }
        __syncthreads();
#pragma unroll
        for (int kk = 0; kk < 2; ++kk) {
            int kb = (kk * 32 + lg * 8) ^ xoff;      // swizzled k-offset (u16)
            bf16x8 af[4], bfr[4];
#pragma unroll
            for (int m = 0; m < 4; ++m)
                af[m] = *reinterpret_cast<const bf16x8*>(&sA[(wr * 64 + m * 16 + lr) * 64 + kb]);
#pragma unroll
            for (int n = 0; n < 4; ++n)
                bfr[n] = *reinterpret_cast<const bf16x8*>(&sB[(wc * 64 + n * 16 + lr) * 64 + kb]);
#pragma unroll
            for (int m = 0; m < 4; ++m)
#pragma unroll
                for (int n = 0; n < 4; ++n)
                    acc[m][n] = __builtin_amdgcn_mfma_f32_16x16x32_bf16(af[m], bfr[n], acc[m][n], 0, 0, 0);
        }
        __syncthreads();
    }

    // ---- LDS-routed epilogue: two phases (wr = 0 then 1), 64 rows each ----
#pragma unroll
    for (int half = 0; half < 2; ++half) {
        if (wr == half) {
#pragma unroll
            for (int m = 0; m < 4; ++m) {
                int rl = m * 16 + lg * 4;            // row within 64-row half
#pragma unroll
                for (int n = 0; n < 4; ++n) {
                    int col = wc * 64 + n * 16 + lr;
#pragma unroll
                    for (int j = 0; j < 4; ++j)
                        st[(rl + j) * 132 + col] = acc[m][n][j] * scale;
                }
            }
        }
        __syncthreads();
        int r = tid >> 2;                 // 0..63
        int c0 = (tid & 3) * 32;          // 0,32,64,96
        size_t grow = (size_t)(by * 128 + half * 64 + r) * N + bx * 128 + c0;
        if constexpr (std::is_same_v<TC, float>) {
#pragma unroll
            for (int g = 0; g < 8; ++g) {
                f32x4 v = *(const f32x4*)&st[r * 132 + c0 + g * 4];
                __builtin_nontemporal_store(v, (f32x4*)&Cb[grow + g * 4]);
            }
        } else {
#pragma unroll
            for (int g = 0; g < 4; ++g) {
                f32x4 a = *(const f32x4*)&st[r * 132 + c0 + g * 8];
                f32x4 b = *(const f32x4*)&st[r * 132 + c0 + g * 8 + 4];
                u16x8 o;
#pragma unroll
                for (int j = 0; j < 4; ++j) { o[j] = f2bf(a[j]); o[4 + j] = f2bf(b[j]); }
                *(u16x8*)&Cb[grow + g * 8] = o;
            }
        }
        __syncthreads();
    }
}

// ---------------- row softmax in place on bf16 [rows, L=2048] ----------------
__global__ __launch_bounds__(256) void softmax_inplace(unsigned short* __restrict__ S, int L) {
    __shared__ float red[8];
    size_t row = blockIdx.x;
    unsigned short* p = S + row * (size_t)L;
    int tid = threadIdx.x;
    int lane = tid & 63;
    int wid = tid >> 6;

    u16x8 u = *(const u16x8*)(p + tid * 8);
    float v[8];
#pragma unroll
    for (int j = 0; j < 8; ++j) v[j] = bf2f(u[j]);

    float mx = v[0];
#pragma unroll
    for (int j = 1; j < 8; ++j) mx = fmaxf(mx, v[j]);
#pragma unroll
    for (int off = 32; off > 0; off >>= 1) mx = fmaxf(mx, __shfl_xor(mx, off));
    if (lane == 0) red[wid] = mx;
    __syncthreads();
    mx = fmaxf(fmaxf(red[0], red[1]), fmaxf(red[2], red[3]));

    float s = 0.f;
#pragma unroll
    for (int j = 0; j < 8; ++j) { v[j] = __expf(v[j] - mx); s += v[j]; }
#pragma unroll
    for (int off = 32; off > 0; off >>= 1) s += __shfl_xor(s, off);
    if (lane == 0) red[4 + wid] = s;
    __syncthreads();
    s = red[4] + red[5] + red[6] + red[7];
    float inv = 1.0f / s;

    u16x8 o;
#pragma unroll
    for (int j = 0; j < 8; ++j) o[j] = f2bf(v[j] * inv);
    *(u16x8*)(p + tid * 8) = o;
}

extern "C" void kernel_launch(void* const* d_in, const int* in_sizes, int n_in,
                              void* d_out, int out_size, void* d_ws, size_t ws_size,
                              hipStream_t stream) {
    constexpr int B = 8, L = 2048, T = 1024, Dh = 1024, Dg = 768, Dp = 256;
    const float* H  = (const float*)d_in[0];
    const float* G  = (const float*)d_in[1];
    const float* Wq = (const float*)d_in[2];
    const float* Wk = (const float*)d_in[3];
    float* Z = (float*)d_out;

    unsigned short* Qbf  = (unsigned short*)d_ws;                 // B*T*Dp
    unsigned short* Kbf  = Qbf  + (size_t)B * T * Dp;             // B*L*Dp
    unsigned short* HT   = Kbf  + (size_t)B * L * Dp;             // B*Dh*L
    unsigned short* Hbf  = HT   + (size_t)B * Dh * L;             // B*L*Dh
    unsigned short* Gbf  = Hbf  + (size_t)B * (size_t)L * Dh;     // B*T*Dg
    unsigned short* Wqbf = Gbf  + (size_t)B * T * Dg;             // Dp*Dg
    unsigned short* Wkbf = Wqbf + (size_t)Dp * Dg;                // Dp*Dh
    unsigned short* S    = Wkbf + (size_t)Dp * Dh;                // B*T*L

    cast_bf16<<<(B * T * Dg / 8 + 255) / 256, 256, 0, stream>>>(G, Gbf, B * T * Dg / 8);
    cast_bf16<<<(Dp * Dg / 8 + 255) / 256, 256, 0, stream>>>(Wq, Wqbf, Dp * Dg / 8);
    cast_bf16<<<(Dp * Dh / 8 + 255) / 256, 256, 0, stream>>>(Wk, Wkbf, Dp * Dh / 8);

    transpose_cast<<<dim3(Dh / 32, L / 32, B), dim3(32, 8), 0, stream>>>(H, HT, Hbf, L, Dh);

    // Q = Gbf @ Wqbf^T  [B*T, Dp], K=Dg
    gemm_lds<unsigned short, false><<<(Dp / 128) * (B * T / 128), 256, 0, stream>>>
        (Gbf, Wqbf, Qbf, Dp, Dg, 0, 0, 0, 1.0f, 1);

    // K = Hbf @ Wkbf^T  [B*L, Dp], K=Dh
    gemm_lds<unsigned short, false><<<(Dp / 128) * (B * L / 128), 256, 0, stream>>>
        (Hbf, Wkbf, Kbf, Dp, Dh, 0, 0, 0, 1.0f, 1);

    // S[b] = Q[b]@K[b]^T / 16  [T,L], K=Dp; XCD-clustered by batch
    gemm_lds<unsigned short, true><<<(L / 128) * (T / 128) * B, 256, 0, stream>>>
        (Qbf, Kbf, S, L, Dp, (long)T * Dp, (long)L * Dp, (long)T * L, 0.0625f, 4);

    // softmax rows (in place)
    softmax_inplace<<<dim3(B * T), 256, 0, stream>>>(S, L);

    // Z[b] = P[b] @ HT[b]^T  [T,Dh], K=L
    gemm_lds<float, true><<<(Dh / 128) * (T / 128) * B, 256, 0, stream>>>
        (S, HT, Z, Dh, L, (long)T * L, (long)Dh * L, (long)T * Dh, 1.0f, 3);
}

// Round 5
// 172.131 us; speedup vs baseline: 1.5699x; 1.3018x over previous
//
#include <hip/hip_runtime.h>
#include <hip/hip_bf16.h>
#include <type_traits>

// Dims: B=8, L=2048, T=1024, Dh=1024, Dg=768, Dp=256
// Pipeline (all-bf16 MFMA GEMMs, m97 structure + BK=64 + XOR-swizzled LDS +
// LDS-routed coalesced epilogue, NO nontemporal stores):
//   Gbf,Wqbf,Wkbf = cast(G,Wq,Wk); [HT,Hbf] = transpose+cast(H)
//   Q = Gbf@Wqbf^T; K = Hbf@Wkbf^T; S = softmax(Q@K^T/16); Z = S@HT^T (f32 out)

typedef float    f32x4  __attribute__((ext_vector_type(4)));
typedef __bf16   bf16x8 __attribute__((ext_vector_type(8)));
typedef unsigned short u16x8 __attribute__((ext_vector_type(8)));

__device__ __forceinline__ unsigned short f2bf(float f) {
    union { float f; unsigned u; } x; x.f = f;
    return (unsigned short)((x.u + 0x7fffu + ((x.u >> 16) & 1u)) >> 16);
}
__device__ __forceinline__ float bf2f(unsigned short u) {
    union { unsigned u; float f; } x; x.u = ((unsigned)u) << 16;
    return x.f;
}

__device__ __forceinline__ void gload_lds16(const unsigned short* g, unsigned short* l) {
    __builtin_amdgcn_global_load_lds(
        (const __attribute__((address_space(1))) void*)g,
        (__attribute__((address_space(3))) void*)l, 16, 0, 0);
}

// ---------------- f32 -> bf16 cast ----------------
__global__ __launch_bounds__(256) void cast_bf16(const float* __restrict__ in,
                                                 unsigned short* __restrict__ out, int n8) {
    int i = blockIdx.x * 256 + threadIdx.x;
    if (i >= n8) return;
    const f32x4* p = (const f32x4*)(in + (size_t)i * 8);
    f32x4 a = p[0], b = p[1];
    u16x8 o;
#pragma unroll
    for (int j = 0; j < 4; ++j) { o[j] = f2bf(a[j]); o[4 + j] = f2bf(b[j]); }
    *(u16x8*)(out + (size_t)i * 8) = o;
}

// ------- transpose + dual cast: H [L,Dh] f32 -> HT [Dh,L] bf16 AND Hbf [L,Dh] bf16 -------
__global__ __launch_bounds__(256) void transpose_cast(const float* __restrict__ H,
                                                      unsigned short* __restrict__ HT,
                                                      unsigned short* __restrict__ Hbf,
                                                      int L, int D) {
    __shared__ float tile[32][33];
    int b = blockIdx.z;
    const float* src = H + (size_t)b * L * D;
    unsigned short* dstT = HT + (size_t)b * L * D;
    unsigned short* dstN = Hbf + (size_t)b * L * D;
    int l0 = blockIdx.y * 32, d0 = blockIdx.x * 32;
    int tx = threadIdx.x, ty = threadIdx.y;
#pragma unroll
    for (int i = ty; i < 32; i += 8) {
        float v = src[(size_t)(l0 + i) * D + d0 + tx];
        tile[i][tx] = v;
        dstN[(size_t)(l0 + i) * D + d0 + tx] = f2bf(v);
    }
    __syncthreads();
#pragma unroll
    for (int i = ty; i < 32; i += 8)
        dstT[(size_t)(d0 + i) * L + l0 + tx] = f2bf(tile[tx][i]);
}

// ---------------- GEMM: C[M,N] = scale * A[M,K] @ B^T[N,K], bf16 in ----------------
// 128x128 tile, BK=64, 4 waves. global_load_lds w16 with pre-swizzled source
// (chunk c8 ^= row&7), frag reads XOR the same involution -> ~2-way banks.
// LDS-routed epilogue: acc -> f32 LDS (stride 132) in two wr-phases, coalesced
// vector stores through L2 (plain stores; NT caused 3.4x write amplification).
template<typename TC, bool BATCH8>
__global__ __launch_bounds__(256) void gemm_lds(const unsigned short* __restrict__ A,
                                                const unsigned short* __restrict__ B,
                                                TC* __restrict__ C,
                                                int N, int K,
                                                long batchA, long batchB, long batchC,
                                                float scale, int gxs) {
    __shared__ __align__(16) char smem_raw[64 * 132 * 4];   // 33792B >= 2*16KB K-tiles
    unsigned short* sA = (unsigned short*)smem_raw;          // 128x64 u16 = 16KB
    unsigned short* sB = sA + 128 * 64;                      // 16KB
    float* st = (float*)smem_raw;                            // epilogue staging 64x132 f32

    int tid = threadIdx.x;
    int wg = blockIdx.x;
    int bz, t;
    if constexpr (BATCH8) { bz = wg & 7; t = wg >> 3; }
    else                  { bz = 0;      t = wg;      }
    int by = t >> gxs;
    int bx = t & ((1 << gxs) - 1);

    const unsigned short* Ab = A + (size_t)bz * batchA + (size_t)by * 128 * K;
    const unsigned short* Bb = B + (size_t)bz * batchB + (size_t)bx * 128 * K;
    TC* Cb = C + (size_t)bz * batchC;

    int lane = tid & 63;
    int wid = tid >> 6;
    int wr = wid >> 1, wc = wid & 1;
    int lr = lane & 15;
    int lg = lane >> 4;          // 0..3
    int xoff = (lane & 7) << 3;  // swizzle XOR for frag reads (u16 units)

    f32x4 acc[4][4] = {};

    for (int k0 = 0; k0 < K; k0 += 64) {
#pragma unroll
        for (int c = 0; c < 4; ++c) {
            int t16 = c * 256 + tid;                 // 16B chunk id in 16KB tile
            int row = t16 >> 3;
            int g8  = (t16 & 7) ^ (row & 7);         // pre-swizzled source chunk
            gload_lds16(Ab + (size_t)row * K + k0 + g8 * 8, sA + t16 * 8);
            gload_lds16(Bb + (size_t)row * K + k0 + g8 * 8, sB + t16 * 8);
        }
        __syncthreads();
#pragma unroll
        for (int kk = 0; kk < 2; ++kk) {
            int kb = (kk * 32 + lg * 8) ^ xoff;      // swizzled k-offset (u16)
            bf16x8 af[4], bfr[4];
#pragma unroll
            for (int m = 0; m < 4; ++m)
                af[m] = *reinterpret_cast<const bf16x8*>(&sA[(wr * 64 + m * 16 + lr) * 64 + kb]);
#pragma unroll
            for (int n = 0; n < 4; ++n)
                bfr[n] = *reinterpret_cast<const bf16x8*>(&sB[(wc * 64 + n * 16 + lr) * 64 + kb]);
#pragma unroll
            for (int m = 0; m < 4; ++m)
#pragma unroll
                for (int n = 0; n < 4; ++n)
                    acc[m][n] = __builtin_amdgcn_mfma_f32_16x16x32_bf16(af[m], bfr[n], acc[m][n], 0, 0, 0);
        }
        __syncthreads();
    }

    // ---- LDS-routed epilogue: two phases (wr = 0 then 1), 64 rows each ----
#pragma unroll
    for (int half = 0; half < 2; ++half) {
        if (wr == half) {
#pragma unroll
            for (int m = 0; m < 4; ++m) {
                int rl = m * 16 + lg * 4;            // row within 64-row half
#pragma unroll
                for (int n = 0; n < 4; ++n) {
                    int col = wc * 64 + n * 16 + lr;
#pragma unroll
                    for (int j = 0; j < 4; ++j)
                        st[(rl + j) * 132 + col] = acc[m][n][j] * scale;
                }
            }
        }
        __syncthreads();
        int r = tid >> 2;                 // 0..63
        int c0 = (tid & 3) * 32;          // 0,32,64,96
        size_t grow = (size_t)(by * 128 + half * 64 + r) * N + bx * 128 + c0;
        if constexpr (std::is_same_v<TC, float>) {
#pragma unroll
            for (int g = 0; g < 8; ++g) {
                f32x4 v = *(const f32x4*)&st[r * 132 + c0 + g * 4];
                *(f32x4*)&Cb[grow + g * 4] = v;
            }
        } else {
#pragma unroll
            for (int g = 0; g < 4; ++g) {
                f32x4 a = *(const f32x4*)&st[r * 132 + c0 + g * 8];
                f32x4 b = *(const f32x4*)&st[r * 132 + c0 + g * 8 + 4];
                u16x8 o;
#pragma unroll
                for (int j = 0; j < 4; ++j) { o[j] = f2bf(a[j]); o[4 + j] = f2bf(b[j]); }
                *(u16x8*)&Cb[grow + g * 8] = o;
            }
        }
        __syncthreads();
    }
}

// ---------------- row softmax in place on bf16 [rows, L=2048] ----------------
__global__ __launch_bounds__(256) void softmax_inplace(unsigned short* __restrict__ S, int L) {
    __shared__ float red[8];
    size_t row = blockIdx.x;
    unsigned short* p = S + row * (size_t)L;
    int tid = threadIdx.x;
    int lane = tid & 63;
    int wid = tid >> 6;

    u16x8 u = *(const u16x8*)(p + tid * 8);
    float v[8];
#pragma unroll
    for (int j = 0; j < 8; ++j) v[j] = bf2f(u[j]);

    float mx = v[0];
#pragma unroll
    for (int j = 1; j < 8; ++j) mx = fmaxf(mx, v[j]);
#pragma unroll
    for (int off = 32; off > 0; off >>= 1) mx = fmaxf(mx, __shfl_xor(mx, off));
    if (lane == 0) red[wid] = mx;
    __syncthreads();
    mx = fmaxf(fmaxf(red[0], red[1]), fmaxf(red[2], red[3]));

    float s = 0.f;
#pragma unroll
    for (int j = 0; j < 8; ++j) { v[j] = __expf(v[j] - mx); s += v[j]; }
#pragma unroll
    for (int off = 32; off > 0; off >>= 1) s += __shfl_xor(s, off);
    if (lane == 0) red[4 + wid] = s;
    __syncthreads();
    s = red[4] + red[5] + red[6] + red[7];
    float inv = 1.0f / s;

    u16x8 o;
#pragma unroll
    for (int j = 0; j < 8; ++j) o[j] = f2bf(v[j] * inv);
    *(u16x8*)(p + tid * 8) = o;
}

extern "C" void kernel_launch(void* const* d_in, const int* in_sizes, int n_in,
                              void* d_out, int out_size, void* d_ws, size_t ws_size,
                              hipStream_t stream) {
    constexpr int B = 8, L = 2048, T = 1024, Dh = 1024, Dg = 768, Dp = 256;
    const float* H  = (const float*)d_in[0];
    const float* G  = (const float*)d_in[1];
    const float* Wq = (const float*)d_in[2];
    const float* Wk = (const float*)d_in[3];
    float* Z = (float*)d_out;

    unsigned short* Qbf  = (unsigned short*)d_ws;                 // B*T*Dp
    unsigned short* Kbf  = Qbf  + (size_t)B * T * Dp;             // B*L*Dp
    unsigned short* HT   = Kbf  + (size_t)B * L * Dp;             // B*Dh*L
    unsigned short* Hbf  = HT   + (size_t)B * Dh * L;             // B*L*Dh
    unsigned short* Gbf  = Hbf  + (size_t)B * (size_t)L * Dh;     // B*T*Dg
    unsigned short* Wqbf = Gbf  + (size_t)B * T * Dg;             // Dp*Dg
    unsigned short* Wkbf = Wqbf + (size_t)Dp * Dg;                // Dp*Dh
    unsigned short* S    = Wkbf + (size_t)Dp * Dh;                // B*T*L

    cast_bf16<<<(B * T * Dg / 8 + 255) / 256, 256, 0, stream>>>(G, Gbf, B * T * Dg / 8);
    cast_bf16<<<(Dp * Dg / 8 + 255) / 256, 256, 0, stream>>>(Wq, Wqbf, Dp * Dg / 8);
    cast_bf16<<<(Dp * Dh / 8 + 255) / 256, 256, 0, stream>>>(Wk, Wkbf, Dp * Dh / 8);

    transpose_cast<<<dim3(Dh / 32, L / 32, B), dim3(32, 8), 0, stream>>>(H, HT, Hbf, L, Dh);

    // Q = Gbf @ Wqbf^T  [B*T, Dp], K=Dg
    gemm_lds<unsigned short, false><<<(Dp / 128) * (B * T / 128), 256, 0, stream>>>
        (Gbf, Wqbf, Qbf, Dp, Dg, 0, 0, 0, 1.0f, 1);

    // K = Hbf @ Wkbf^T  [B*L, Dp], K=Dh
    gemm_lds<unsigned short, false><<<(Dp / 128) * (B * L / 128), 256, 0, stream>>>
        (Hbf, Wkbf, Kbf, Dp, Dh, 0, 0, 0, 1.0f, 1);

    // S[b] = Q[b]@K[b]^T / 16  [T,L], K=Dp; XCD-clustered by batch
    gemm_lds<unsigned short, true><<<(L / 128) * (T / 128) * B, 256, 0, stream>>>
        (Qbf, Kbf, S, L, Dp, (long)T * Dp, (long)L * Dp, (long)T * L, 0.0625f, 4);

    // softmax rows (in place)
    softmax_inplace<<<dim3(B * T), 256, 0, stream>>>(S, L);

    // Z[b] = P[b] @ HT[b]^T  [T,Dh], K=L
    gemm_lds<float, true><<<(Dh / 128) * (T / 128) * B, 256, 0, stream>>>
        (S, HT, Z, Dh, L, (long)T * L, (long)Dh * L, (long)T * Dh, 1.0f, 3);
}